// Round 9
// baseline (92.660 us; speedup 1.0000x reference)
//
#include <hip/hip_runtime.h>
#include <hip/hip_bf16.h>

// GraphConv: out[b,n,f] = relu( sum_{k,d} x[b, nbr[n,k], d] * W[k,d,f] + bias[f] )
// B=4, N=50000, D=32, K=16, F=32.  M = B*N = 200000 rows, contraction = 512.
//
// Round 9: round-8 value path + deep async gather pipeline.
//  - A-tile staged via global_load_lds (per-lane global addr, linear LDS dest
//    = A-fragment order) into a per-wave 4-deep ring; counted vmcnt keeps 3
//    stage groups in flight. No __syncthreads (slots are wave-private).
//  - B-fragments pre-transposed by prep_w into fragment-coalesced order
//    (64 lanes x 16B contiguous per load), loaded 4 iters ahead (static ring).
// Bit-identical math to the round-8 PASS (f32 LDS round-trip is exact).

typedef __attribute__((ext_vector_type(8))) short bf16x8;
typedef __attribute__((ext_vector_type(4))) float f32x4;
typedef unsigned int u32;

constexpr int B_ = 4, N_ = 50000, D_ = 32, K_ = 16, F_ = 32;
constexpr int M_ = B_ * N_;                      // 200000
constexpr int ROWS_PER_WAVE = 16;
constexpr int WAVES = 4;
constexpr int ROWS_PER_BLOCK = ROWS_PER_WAVE * WAVES;  // 64
constexpr int PIPE = 4;                          // stage-ring depth

__device__ __forceinline__ short f2bf_rne(float f) {
    union { float f; unsigned u; } v; v.f = f;
    unsigned r = v.u + 0x7FFFu + ((v.u >> 16) & 1u);
    return (short)(r >> 16);
}

__device__ __forceinline__ void stage16(const float* g, float* l) {
    __builtin_amdgcn_global_load_lds(
        (const __attribute__((address_space(1))) u32*)g,
        (__attribute__((address_space(3))) u32*)l,
        16, 0, 0);
}

// ---- prep: W (f32 [k][d][f]) -> bf16 B-fragments in lane-coalesced order ----
// wsf[((kk*2 + h)*64 + lane)*8 + dd] = bf16(kern[kk][ (lane>>4)*8+dd ][ h*16 + (lane&15) ])
// so the B-load for (kk, half h) is 64 lanes x 16B contiguous (1 KB).
__global__ __launch_bounds__(256) void prep_w(const float* __restrict__ kern,
                                              short* __restrict__ wsf) {
    int e = blockIdx.x * 256 + threadIdx.x;      // 64 blocks x 256 = 16384
    int kk = e >> 10;          // / (D_*F_)
    int d  = (e >> 5) & 31;
    int f  = e & 31;
    int h    = f >> 4;
    int lane = ((d >> 3) << 4) | (f & 15);
    int dd   = d & 7;
    wsf[(((kk * 2 + h) * 64) + lane) * 8 + dd] = f2bf_rne(kern[e]);
}

__global__ __launch_bounds__(256) void graphconv_mfma(
    const float* __restrict__ x,
    const int*   __restrict__ nbr,
    const short* __restrict__ wsf,
    const float* __restrict__ bias,
    float*       __restrict__ out)
{
    // per-wave 4-deep A ring: slot = 512 floats (2 KB): [0..255]=xa halves
    // by lane, [256..511]=xb halves by lane.  4 waves x 8 KB = 32 KB.
    __shared__ __align__(16) float aring[WAVES][PIPE][512];

    // int64-pushed-as-int32 detection (odd dwords are zero high words).
    const bool is64 = (nbr[1] | nbr[3] | nbr[5] | nbr[7] |
                       nbr[9] | nbr[11] | nbr[13] | nbr[15]) == 0;
    const int istride = is64 ? 2 : 1;

    const int lane = threadIdx.x & 63;
    const int wid  = threadIdx.x >> 6;
    const int m0   = blockIdx.x * ROWS_PER_BLOCK + wid * ROWS_PER_WAVE;

    const int r     = lane & 15;   // A-row / B-col this lane serves
    const int chunk = lane >> 4;   // 8-wide d-chunk
    const int m     = m0 + r;
    const int b     = m / N_;
    const int n     = m - b * N_;

    int idxs[K_];
#pragma unroll
    for (int kk = 0; kk < K_; ++kk)
        idxs[kk] = nbr[(size_t)(n * K_ + kk) * istride];

    const float* xbase = x + (size_t)b * (N_ * D_) + chunk * 8;

    bf16x8 bring[PIPE][2];
    f32x4 acc0 = {0.f, 0.f, 0.f, 0.f};
    f32x4 acc1 = {0.f, 0.f, 0.f, 0.f};

    // ---- prologue: issue stage+B groups for kk = 0..3 ----
#pragma unroll
    for (int p = 0; p < PIPE; ++p) {
        const float* xr = xbase + (size_t)idxs[p] * D_;
        stage16(xr,     &aring[wid][p][0]);
        stage16(xr + 4, &aring[wid][p][256]);
        bring[p][0] = *reinterpret_cast<const bf16x8*>(wsf + (p * 2 + 0) * 512 + lane * 8);
        bring[p][1] = *reinterpret_cast<const bf16x8*>(wsf + (p * 2 + 1) * 512 + lane * 8);
    }

#pragma unroll
    for (int kk = 0; kk < K_; ++kk) {
        // wait until stage(kk) complete; count ONLY stage ops issued after it
        // (2 per remaining group) so the count is robust to B-load placement.
        if      (kk < 13)  asm volatile("s_waitcnt vmcnt(6)" ::: "memory");
        else if (kk == 13) asm volatile("s_waitcnt vmcnt(4)" ::: "memory");
        else if (kk == 14) asm volatile("s_waitcnt vmcnt(2)" ::: "memory");
        else               asm volatile("s_waitcnt vmcnt(0)" ::: "memory");

        const int s = kk & (PIPE - 1);
        f32x4 xa = *reinterpret_cast<const f32x4*>(&aring[wid][s][lane * 4]);
        f32x4 xb = *reinterpret_cast<const f32x4*>(&aring[wid][s][256 + lane * 4]);

        unsigned p0, p1, p2, p3;
        asm("v_cvt_pk_bf16_f32 %0, %1, %2" : "=v"(p0) : "v"(xa.x), "v"(xa.y));
        asm("v_cvt_pk_bf16_f32 %0, %1, %2" : "=v"(p1) : "v"(xa.z), "v"(xa.w));
        asm("v_cvt_pk_bf16_f32 %0, %1, %2" : "=v"(p2) : "v"(xb.x), "v"(xb.y));
        asm("v_cvt_pk_bf16_f32 %0, %1, %2" : "=v"(p3) : "v"(xb.z), "v"(xb.w));
        union { unsigned u[4]; bf16x8 v; } af;
        af.u[0] = p0; af.u[1] = p1; af.u[2] = p2; af.u[3] = p3;

        acc0 = __builtin_amdgcn_mfma_f32_16x16x32_bf16(af.v, bring[s][0], acc0, 0, 0, 0);
        acc1 = __builtin_amdgcn_mfma_f32_16x16x32_bf16(af.v, bring[s][1], acc1, 0, 0, 0);

        // issue group kk+PIPE (ds_reads above already drained via lgkmcnt
        // before the cvt, so overwriting the slot is safe)
        if (kk + PIPE < K_) {
            const int kn = kk + PIPE;
            const float* xr = xbase + (size_t)idxs[kn] * D_;
            stage16(xr,     &aring[wid][s][0]);
            stage16(xr + 4, &aring[wid][s][256]);
            bring[s][0] = *reinterpret_cast<const bf16x8*>(wsf + (kn * 2 + 0) * 512 + lane * 8);
            bring[s][1] = *reinterpret_cast<const bf16x8*>(wsf + (kn * 2 + 1) * 512 + lane * 8);
        }
    }

    // ---- epilogue: C layout col=lane&15, row=(lane>>4)*4+reg ----
    const float bv0 = bias[r];
    const float bv1 = bias[16 + r];
    const int rowbase = m0 + (lane >> 4) * 4;
#pragma unroll
    for (int j = 0; j < 4; ++j) {
        const size_t o = (size_t)(rowbase + j) * F_;
        float v0 = acc0[j] + bv0;
        float v1 = acc1[j] + bv1;
        out[o + r]      = v0 > 0.f ? v0 : 0.f;
        out[o + 16 + r] = v1 > 0.f ? v1 : 0.f;
    }
}

extern "C" void kernel_launch(void* const* d_in, const int* in_sizes, int n_in,
                              void* d_out, int out_size, void* d_ws, size_t ws_size,
                              hipStream_t stream) {
    const float* x    = (const float*)d_in[0];
    const int*   nbr  = (const int*)d_in[1];
    const float* kern = (const float*)d_in[2];
    const float* bias = (const float*)d_in[3];
    float* out = (float*)d_out;
    short* wsf = (short*)d_ws;   // needs 16*2*64*8*2 = 32768 bytes

    prep_w<<<dim3(K_ * D_ * F_ / 256), 256, 0, stream>>>(kern, wsf);
    graphconv_mfma<<<dim3(M_ / ROWS_PER_BLOCK), 256, 0, stream>>>(
        x, nbr, wsf, bias, out);
}

// Round 10
// 50.782 us; speedup vs baseline: 1.8246x; 1.8246x over previous
//
#include <hip/hip_runtime.h>
#include <hip/hip_bf16.h>

// GraphConv: out[b,n,f] = relu( sum_{k,d} x[b, nbr[n,k], d] * W[k,d,f] + bias[f] )
// B=4, N=50000, D=32, K=16, F=32.  M = B*N = 200000 rows, contraction = 512.
//
// Round 10: request-count reduction. Evidence: r4/r8/r9 (serial / +occupancy /
// +async-pipeline) all ~88us => not latency-x-concurrency bound; bottleneck is
// the per-CU memory-request stream. Changes (all value-path bit-identical to
// the verified r8/r9 PASSes):
//   1) prep converts x to bf16 (RNE, same rounding the verified kernels did
//      in-loop): A-gather = ONE bf16x8 load/kk (16 lines vs 32), bytes /2,
//      per-batch working set 3.2MB fits the 4MB XCD L2.
//   2) prep compacts nbr to dense int32: indices loaded as 4x int4 per lane
//      (64 line-requests vs 256 redundant dword loads).
//   3) B-operand: round-9 verified wsf fragment-coalesced layout (L1-hot).
// No LDS, no barriers. Fallback to verified round-8 path if ws_size < 25.6MB.

typedef __attribute__((ext_vector_type(8))) short bf16x8;
typedef __attribute__((ext_vector_type(4))) short s16x4;
typedef __attribute__((ext_vector_type(4))) float f32x4;
typedef __attribute__((ext_vector_type(4))) int   i32x4;

constexpr int B_ = 4, N_ = 50000, D_ = 32, K_ = 16, F_ = 32;
constexpr int M_ = B_ * N_;                      // 200000
constexpr int ROWS_PER_BLOCK = 64;               // 4 waves x 16 rows

// ---- workspace layout (bytes) ----
constexpr size_t WSF_OFF = 0;                        // 32768 B  (B-fragments)
constexpr size_t X16_OFF = 32768;                    // 12,800,000 B (x bf16)
constexpr size_t NBR_OFF = X16_OFF + 12800000;       // 12,800,000 B (nbr i32)
constexpr size_t WS_NEED = NBR_OFF + 12800000;       // 25,632,768 B

__device__ __forceinline__ short f2bf_rne(float f) {
    union { float f; unsigned u; } v; v.f = f;
    unsigned r = v.u + 0x7FFFu + ((v.u >> 16) & 1u);
    return (short)(r >> 16);
}

// ================= fast path =================

__global__ __launch_bounds__(256) void prep_all(
    const float* __restrict__ x, const int* __restrict__ nbr,
    const float* __restrict__ kern,
    short* __restrict__ wsf, short* __restrict__ x16, int* __restrict__ nbr32)
{
    const int stride = gridDim.x * 256;
    const int t = blockIdx.x * 256 + threadIdx.x;

    // x: f32 -> bf16, vectorized 4-wide (1,600,000 vec4)
    const f32x4* x4 = (const f32x4*)x;
    s16x4* xo = (s16x4*)x16;
    for (int i = t; i < (B_ * N_ * D_) / 4; i += stride) {
        f32x4 v = x4[i];
        s16x4 o = { f2bf_rne(v.x), f2bf_rne(v.y), f2bf_rne(v.z), f2bf_rne(v.w) };
        xo[i] = o;
    }

    // nbr: int64-or-int32 -> dense int32 (200,000 vec4)
    const bool is64 = (nbr[1] | nbr[3] | nbr[5] | nbr[7] |
                       nbr[9] | nbr[11] | nbr[13] | nbr[15]) == 0;
    i32x4* nd = (i32x4*)nbr32;
    const i32x4* ns = (const i32x4*)nbr;
    if (is64) {
        for (int i = t; i < (N_ * K_) / 4; i += stride) {
            i32x4 a = ns[i * 2], c = ns[i * 2 + 1];
            nd[i] = (i32x4){a.x, a.z, c.x, c.z};
        }
    } else {
        for (int i = t; i < (N_ * K_) / 4; i += stride) nd[i] = ns[i];
    }

    // W -> wsf, round-9 verified fragment-coalesced layout:
    // wsf[((kk*2+h)*64 + lane)*8 + dd] = bf16(kern[kk][(lane>>4)*8+dd][h*16+(lane&15)])
    for (int e = t; e < K_ * D_ * F_; e += stride) {
        int kk = e >> 10, d = (e >> 5) & 31, f = e & 31;
        int h = f >> 4, lane = ((d >> 3) << 4) | (f & 15), dd = d & 7;
        wsf[(((kk * 2 + h) * 64) + lane) * 8 + dd] = f2bf_rne(kern[e]);
    }
}

__global__ __launch_bounds__(256) void graphconv_fast(
    const short* __restrict__ x16, const int* __restrict__ nbr32,
    const short* __restrict__ wsf, const float* __restrict__ bias,
    float* __restrict__ out)
{
    const int lane  = threadIdx.x & 63;
    const int wid   = threadIdx.x >> 6;
    const int m0    = blockIdx.x * ROWS_PER_BLOCK + wid * 16;
    const int r     = lane & 15;   // A-row / B-col this lane serves
    const int chunk = lane >> 4;   // 8-wide d-chunk
    const int m     = m0 + r;
    const int b     = m / N_;
    const int n     = m - b * N_;

    // all 16 indices in 4 vector loads (16 lines/instr, 4 instrs)
    const i32x4* ip = (const i32x4*)(nbr32 + (size_t)n * K_);
    i32x4 q0 = ip[0], q1 = ip[1], q2 = ip[2], q3 = ip[3];
    const int idxs[K_] = {q0.x, q0.y, q0.z, q0.w, q1.x, q1.y, q1.z, q1.w,
                          q2.x, q2.y, q2.z, q2.w, q3.x, q3.y, q3.z, q3.w};

    const short* xb = x16 + (size_t)b * (N_ * D_) + chunk * 8;
    const short* bf = wsf + lane * 8;

    f32x4 acc0 = {0.f, 0.f, 0.f, 0.f};
    f32x4 acc1 = {0.f, 0.f, 0.f, 0.f};

#pragma unroll
    for (int kk = 0; kk < K_; ++kk) {
        bf16x8 a  = *reinterpret_cast<const bf16x8*>(xb + (size_t)idxs[kk] * D_);
        bf16x8 b0 = *reinterpret_cast<const bf16x8*>(bf + (kk * 2 + 0) * 512);
        bf16x8 b1 = *reinterpret_cast<const bf16x8*>(bf + (kk * 2 + 1) * 512);
        acc0 = __builtin_amdgcn_mfma_f32_16x16x32_bf16(a, b0, acc0, 0, 0, 0);
        acc1 = __builtin_amdgcn_mfma_f32_16x16x32_bf16(a, b1, acc1, 0, 0, 0);
    }

    // epilogue (verified): C col = lane&15, row = (lane>>4)*4 + j
    const float bv0 = bias[r];
    const float bv1 = bias[16 + r];
    const int rowbase = m0 + chunk * 4;
#pragma unroll
    for (int j = 0; j < 4; ++j) {
        const size_t o = (size_t)(rowbase + j) * F_;
        float v0 = acc0[j] + bv0;
        float v1 = acc1[j] + bv1;
        out[o + r]      = v0 > 0.f ? v0 : 0.f;
        out[o + 16 + r] = v1 > 0.f ? v1 : 0.f;
    }
}

// ================= fallback path (verified round-8, needs only 40KB ws) =====

constexpr int DPAD = 40;
constexpr int KSTRIDE = F_ * DPAD;               // 1280 shorts per k-slab

__global__ __launch_bounds__(256) void prep_w8(const float* __restrict__ kern,
                                               short* __restrict__ ws16) {
    int e = blockIdx.x * 256 + threadIdx.x;
    int kk = e >> 10, d = (e >> 5) & 31, f = e & 31;
    ws16[kk * KSTRIDE + f * DPAD + d] = f2bf_rne(kern[e]);
}

__global__ __launch_bounds__(256) void graphconv_mfma8(
    const float* __restrict__ x, const int* __restrict__ nbr,
    const short* __restrict__ ws16, const float* __restrict__ bias,
    float* __restrict__ out)
{
    const bool is64 = (nbr[1] | nbr[3] | nbr[5] | nbr[7] |
                       nbr[9] | nbr[11] | nbr[13] | nbr[15]) == 0;
    const int istride = is64 ? 2 : 1;

    const int lane = threadIdx.x & 63;
    const int wid  = threadIdx.x >> 6;
    const int m0   = blockIdx.x * ROWS_PER_BLOCK + wid * 16;
    const int r = lane & 15, chunk = lane >> 4;
    const int m = m0 + r;
    const int b = m / N_;
    const int n = m - b * N_;

    int idxs[K_];
#pragma unroll
    for (int kk = 0; kk < K_; ++kk)
        idxs[kk] = nbr[(size_t)(n * K_ + kk) * istride];

    const float* xbase = x + (size_t)b * (N_ * D_) + chunk * 8;
    const short* bcol0 = ws16 + r * DPAD + chunk * 8;
    const short* bcol1 = ws16 + (16 + r) * DPAD + chunk * 8;

    f32x4 acc0 = {0.f, 0.f, 0.f, 0.f};
    f32x4 acc1 = {0.f, 0.f, 0.f, 0.f};

#pragma unroll
    for (int kk = 0; kk < K_; ++kk) {
        const float* xr = xbase + (size_t)idxs[kk] * D_;
        f32x4 xa = *reinterpret_cast<const f32x4*>(xr);
        f32x4 xb = *reinterpret_cast<const f32x4*>(xr + 4);
        unsigned p0, p1, p2, p3;
        asm("v_cvt_pk_bf16_f32 %0, %1, %2" : "=v"(p0) : "v"(xa.x), "v"(xa.y));
        asm("v_cvt_pk_bf16_f32 %0, %1, %2" : "=v"(p1) : "v"(xa.z), "v"(xa.w));
        asm("v_cvt_pk_bf16_f32 %0, %1, %2" : "=v"(p2) : "v"(xb.x), "v"(xb.y));
        asm("v_cvt_pk_bf16_f32 %0, %1, %2" : "=v"(p3) : "v"(xb.z), "v"(xb.w));
        union { unsigned u[4]; bf16x8 v; } af;
        af.u[0] = p0; af.u[1] = p1; af.u[2] = p2; af.u[3] = p3;
        bf16x8 b0 = *reinterpret_cast<const bf16x8*>(bcol0 + kk * KSTRIDE);
        bf16x8 b1 = *reinterpret_cast<const bf16x8*>(bcol1 + kk * KSTRIDE);
        acc0 = __builtin_amdgcn_mfma_f32_16x16x32_bf16(af.v, b0, acc0, 0, 0, 0);
        acc1 = __builtin_amdgcn_mfma_f32_16x16x32_bf16(af.v, b1, acc1, 0, 0, 0);
    }

    const float bv0 = bias[r];
    const float bv1 = bias[16 + r];
    const int rowbase = m0 + chunk * 4;
#pragma unroll
    for (int j = 0; j < 4; ++j) {
        const size_t o = (size_t)(rowbase + j) * F_;
        float v0 = acc0[j] + bv0;
        float v1 = acc1[j] + bv1;
        out[o + r]      = v0 > 0.f ? v0 : 0.f;
        out[o + 16 + r] = v1 > 0.f ? v1 : 0.f;
    }
}

// ================= launch =================

extern "C" void kernel_launch(void* const* d_in, const int* in_sizes, int n_in,
                              void* d_out, int out_size, void* d_ws, size_t ws_size,
                              hipStream_t stream) {
    const float* x    = (const float*)d_in[0];
    const int*   nbr  = (const int*)d_in[1];
    const float* kern = (const float*)d_in[2];
    const float* bias = (const float*)d_in[3];
    float* out = (float*)d_out;

    if (ws_size >= WS_NEED) {
        char* ws = (char*)d_ws;
        short* wsf   = (short*)(ws + WSF_OFF);
        short* x16   = (short*)(ws + X16_OFF);
        int*   nbr32 = (int*)(ws + NBR_OFF);
        prep_all<<<dim3(1024), 256, 0, stream>>>(x, nbr, kern, wsf, x16, nbr32);
        graphconv_fast<<<dim3(M_ / ROWS_PER_BLOCK), 256, 0, stream>>>(
            x16, nbr32, wsf, bias, out);
    } else {
        short* ws16 = (short*)d_ws;   // 40960 B
        prep_w8<<<dim3(K_ * D_ * F_ / 256), 256, 0, stream>>>(kern, ws16);
        graphconv_mfma8<<<dim3(M_ / ROWS_PER_BLOCK), 256, 0, stream>>>(
            x, nbr, ws16, bias, out);
    }
}

// Round 11
// 44.984 us; speedup vs baseline: 2.0598x; 1.1289x over previous
//
#include <hip/hip_runtime.h>
#include <hip/hip_bf16.h>

// GraphConv: out[b,n,f] = relu( sum_{k,d} x[b, nbr[n,k], d] * W[k,d,f] + bias[f] )
// B=4, N=50000, D=32, K=16, F=32.  M = B*N = 200000 rows, contraction = 512.
//
// Round 11 = round 10 (PASS, 50.8us) + ONE change: B-fragments served from
// LDS instead of global. Audit: B-loads were 512 line-requests/wave (2x the
// gather's 256) on the TA path, which r4/r8/r9/r10 evidence shows is the
// bottleneck (time ~ request count). ds_read bypasses TA; the wsf layout read
// at byte addr slab+lane*16 is fully sequential (LDS-peak, conflict-free).
// LDS image is an IDENTITY copy of the verified wsf array (lb[i]=wsf[i], no
// index algebra -- rounds 6/7 lesson), read offsets textually identical to
// round 10's verified global read.

typedef __attribute__((ext_vector_type(8))) short bf16x8;
typedef __attribute__((ext_vector_type(4))) short s16x4;
typedef __attribute__((ext_vector_type(4))) float f32x4;
typedef __attribute__((ext_vector_type(4))) int   i32x4;

constexpr int B_ = 4, N_ = 50000, D_ = 32, K_ = 16, F_ = 32;
constexpr int M_ = B_ * N_;                      // 200000
constexpr int ROWS_PER_BLOCK = 64;               // 4 waves x 16 rows

// ---- workspace layout (bytes) ----
constexpr size_t WSF_OFF = 0;                        // 32768 B  (B-fragments)
constexpr size_t X16_OFF = 32768;                    // 12,800,000 B (x bf16)
constexpr size_t NBR_OFF = X16_OFF + 12800000;       // 12,800,000 B (nbr i32)
constexpr size_t WS_NEED = NBR_OFF + 12800000;       // 25,632,768 B

__device__ __forceinline__ short f2bf_rne(float f) {
    union { float f; unsigned u; } v; v.f = f;
    unsigned r = v.u + 0x7FFFu + ((v.u >> 16) & 1u);
    return (short)(r >> 16);
}

// ================= fast path =================

__global__ __launch_bounds__(256) void prep_all(
    const float* __restrict__ x, const int* __restrict__ nbr,
    const float* __restrict__ kern,
    short* __restrict__ wsf, short* __restrict__ x16, int* __restrict__ nbr32)
{
    const int stride = gridDim.x * 256;
    const int t = blockIdx.x * 256 + threadIdx.x;

    // x: f32 -> bf16, vectorized 4-wide (1,600,000 vec4)
    const f32x4* x4 = (const f32x4*)x;
    s16x4* xo = (s16x4*)x16;
    for (int i = t; i < (B_ * N_ * D_) / 4; i += stride) {
        f32x4 v = x4[i];
        s16x4 o = { f2bf_rne(v.x), f2bf_rne(v.y), f2bf_rne(v.z), f2bf_rne(v.w) };
        xo[i] = o;
    }

    // nbr: int64-or-int32 -> dense int32 (200,000 vec4)
    const bool is64 = (nbr[1] | nbr[3] | nbr[5] | nbr[7] |
                       nbr[9] | nbr[11] | nbr[13] | nbr[15]) == 0;
    i32x4* nd = (i32x4*)nbr32;
    const i32x4* ns = (const i32x4*)nbr;
    if (is64) {
        for (int i = t; i < (N_ * K_) / 4; i += stride) {
            i32x4 a = ns[i * 2], c = ns[i * 2 + 1];
            nd[i] = (i32x4){a.x, a.z, c.x, c.z};
        }
    } else {
        for (int i = t; i < (N_ * K_) / 4; i += stride) nd[i] = ns[i];
    }

    // W -> wsf, verified fragment-coalesced layout:
    // wsf[((kk*2+h)*64 + lane)*8 + dd] = bf16(kern[kk][(lane>>4)*8+dd][h*16+(lane&15)])
    for (int e = t; e < K_ * D_ * F_; e += stride) {
        int kk = e >> 10, d = (e >> 5) & 31, f = e & 31;
        int h = f >> 4, lane = ((d >> 3) << 4) | (f & 15), dd = d & 7;
        wsf[(((kk * 2 + h) * 64) + lane) * 8 + dd] = f2bf_rne(kern[e]);
    }
}

__global__ __launch_bounds__(256) void graphconv_fast(
    const short* __restrict__ x16, const int* __restrict__ nbr32,
    const short* __restrict__ wsf, const float* __restrict__ bias,
    float* __restrict__ out)
{
    // identity image of wsf (16384 shorts = 32 KB); ds_read at slab+lane*16
    // is fully sequential per instruction -> LDS-peak, no conflicts.
    __shared__ __align__(16) short lb[K_ * 2 * 64 * 8];
    {
        const bf16x8* src = (const bf16x8*)wsf;
        bf16x8* dst = (bf16x8*)lb;
#pragma unroll
        for (int i = 0; i < 8; ++i)
            dst[threadIdx.x + i * 256] = src[threadIdx.x + i * 256];
    }
    __syncthreads();

    const int lane  = threadIdx.x & 63;
    const int wid   = threadIdx.x >> 6;
    const int m0    = blockIdx.x * ROWS_PER_BLOCK + wid * 16;
    const int r     = lane & 15;   // A-row / B-col this lane serves
    const int chunk = lane >> 4;   // 8-wide d-chunk
    const int m     = m0 + r;
    const int b     = m / N_;
    const int n     = m - b * N_;

    // all 16 indices in 4 vector loads
    const i32x4* ip = (const i32x4*)(nbr32 + (size_t)n * K_);
    i32x4 q0 = ip[0], q1 = ip[1], q2 = ip[2], q3 = ip[3];
    const int idxs[K_] = {q0.x, q0.y, q0.z, q0.w, q1.x, q1.y, q1.z, q1.w,
                          q2.x, q2.y, q2.z, q2.w, q3.x, q3.y, q3.z, q3.w};

    const short* xb = x16 + (size_t)b * (N_ * D_) + chunk * 8;
    const short* bf = lb + lane * 8;

    f32x4 acc0 = {0.f, 0.f, 0.f, 0.f};
    f32x4 acc1 = {0.f, 0.f, 0.f, 0.f};

#pragma unroll
    for (int kk = 0; kk < K_; ++kk) {
        bf16x8 a  = *reinterpret_cast<const bf16x8*>(xb + (size_t)idxs[kk] * D_);
        bf16x8 b0 = *reinterpret_cast<const bf16x8*>(bf + (kk * 2 + 0) * 512);
        bf16x8 b1 = *reinterpret_cast<const bf16x8*>(bf + (kk * 2 + 1) * 512);
        acc0 = __builtin_amdgcn_mfma_f32_16x16x32_bf16(a, b0, acc0, 0, 0, 0);
        acc1 = __builtin_amdgcn_mfma_f32_16x16x32_bf16(a, b1, acc1, 0, 0, 0);
    }

    // epilogue (verified): C col = lane&15, row = (lane>>4)*4 + j
    const float bv0 = bias[r];
    const float bv1 = bias[16 + r];
    const int rowbase = m0 + chunk * 4;
#pragma unroll
    for (int j = 0; j < 4; ++j) {
        const size_t o = (size_t)(rowbase + j) * F_;
        float v0 = acc0[j] + bv0;
        float v1 = acc1[j] + bv1;
        out[o + r]      = v0 > 0.f ? v0 : 0.f;
        out[o + 16 + r] = v1 > 0.f ? v1 : 0.f;
    }
}

// ================= fallback path (verified round-8, needs only 40KB ws) =====

constexpr int DPAD = 40;
constexpr int KSTRIDE = F_ * DPAD;               // 1280 shorts per k-slab

__global__ __launch_bounds__(256) void prep_w8(const float* __restrict__ kern,
                                               short* __restrict__ ws16) {
    int e = blockIdx.x * 256 + threadIdx.x;
    int kk = e >> 10, d = (e >> 5) & 31, f = e & 31;
    ws16[kk * KSTRIDE + f * DPAD + d] = f2bf_rne(kern[e]);
}

__global__ __launch_bounds__(256) void graphconv_mfma8(
    const float* __restrict__ x, const int* __restrict__ nbr,
    const short* __restrict__ ws16, const float* __restrict__ bias,
    float* __restrict__ out)
{
    const bool is64 = (nbr[1] | nbr[3] | nbr[5] | nbr[7] |
                       nbr[9] | nbr[11] | nbr[13] | nbr[15]) == 0;
    const int istride = is64 ? 2 : 1;

    const int lane = threadIdx.x & 63;
    const int wid  = threadIdx.x >> 6;
    const int m0   = blockIdx.x * ROWS_PER_BLOCK + wid * 16;
    const int r = lane & 15, chunk = lane >> 4;
    const int m = m0 + r;
    const int b = m / N_;
    const int n = m - b * N_;

    int idxs[K_];
#pragma unroll
    for (int kk = 0; kk < K_; ++kk)
        idxs[kk] = nbr[(size_t)(n * K_ + kk) * istride];

    const float* xbase = x + (size_t)b * (N_ * D_) + chunk * 8;
    const short* bcol0 = ws16 + r * DPAD + chunk * 8;
    const short* bcol1 = ws16 + (16 + r) * DPAD + chunk * 8;

    f32x4 acc0 = {0.f, 0.f, 0.f, 0.f};
    f32x4 acc1 = {0.f, 0.f, 0.f, 0.f};

#pragma unroll
    for (int kk = 0; kk < K_; ++kk) {
        const float* xr = xbase + (size_t)idxs[kk] * D_;
        f32x4 xa = *reinterpret_cast<const f32x4*>(xr);
        f32x4 xb = *reinterpret_cast<const f32x4*>(xr + 4);
        unsigned p0, p1, p2, p3;
        asm("v_cvt_pk_bf16_f32 %0, %1, %2" : "=v"(p0) : "v"(xa.x), "v"(xa.y));
        asm("v_cvt_pk_bf16_f32 %0, %1, %2" : "=v"(p1) : "v"(xa.z), "v"(xa.w));
        asm("v_cvt_pk_bf16_f32 %0, %1, %2" : "=v"(p2) : "v"(xb.x), "v"(xb.y));
        asm("v_cvt_pk_bf16_f32 %0, %1, %2" : "=v"(p3) : "v"(xb.z), "v"(xb.w));
        union { unsigned u[4]; bf16x8 v; } af;
        af.u[0] = p0; af.u[1] = p1; af.u[2] = p2; af.u[3] = p3;
        bf16x8 b0 = *reinterpret_cast<const bf16x8*>(bcol0 + kk * KSTRIDE);
        bf16x8 b1 = *reinterpret_cast<const bf16x8*>(bcol1 + kk * KSTRIDE);
        acc0 = __builtin_amdgcn_mfma_f32_16x16x32_bf16(af.v, b0, acc0, 0, 0, 0);
        acc1 = __builtin_amdgcn_mfma_f32_16x16x32_bf16(af.v, b1, acc1, 0, 0, 0);
    }

    const float bv0 = bias[r];
    const float bv1 = bias[16 + r];
    const int rowbase = m0 + chunk * 4;
#pragma unroll
    for (int j = 0; j < 4; ++j) {
        const size_t o = (size_t)(rowbase + j) * F_;
        float v0 = acc0[j] + bv0;
        float v1 = acc1[j] + bv1;
        out[o + r]      = v0 > 0.f ? v0 : 0.f;
        out[o + 16 + r] = v1 > 0.f ? v1 : 0.f;
    }
}

// ================= launch =================

extern "C" void kernel_launch(void* const* d_in, const int* in_sizes, int n_in,
                              void* d_out, int out_size, void* d_ws, size_t ws_size,
                              hipStream_t stream) {
    const float* x    = (const float*)d_in[0];
    const int*   nbr  = (const int*)d_in[1];
    const float* kern = (const float*)d_in[2];
    const float* bias = (const float*)d_in[3];
    float* out = (float*)d_out;

    if (ws_size >= WS_NEED) {
        char* ws = (char*)d_ws;
        short* wsf   = (short*)(ws + WSF_OFF);
        short* x16   = (short*)(ws + X16_OFF);
        int*   nbr32 = (int*)(ws + NBR_OFF);
        prep_all<<<dim3(1024), 256, 0, stream>>>(x, nbr, kern, wsf, x16, nbr32);
        graphconv_fast<<<dim3(M_ / ROWS_PER_BLOCK), 256, 0, stream>>>(
            x16, nbr32, wsf, bias, out);
    } else {
        short* ws16 = (short*)d_ws;   // 40960 B
        prep_w8<<<dim3(K_ * D_ * F_ / 256), 256, 0, stream>>>(kern, ws16);
        graphconv_mfma8<<<dim3(M_ / ROWS_PER_BLOCK), 256, 0, stream>>>(
            x, nbr, ws16, bias, out);
    }
}

// Round 12
// 44.111 us; speedup vs baseline: 2.1006x; 1.0198x over previous
//
#include <hip/hip_runtime.h>
#include <hip/hip_bf16.h>

// GraphConv: out[b,n,f] = relu( sum_{k,d} x[b, nbr[n,k], d] * W[k,d,f] + bias[f] )
// B=4, N=50000, D=32, K=16, F=32.  M = B*N = 200000 rows, contraction = 512.
//
// Round 12 = round 11 (PASS, 45.0us) + ONE change: bijective XCD-chunked
// block swizzle. Theory: in-flight blocks (~40% of grid) span ~2 batches per
// XCD -> gather working set ~6.4MB > 4MiB XCD-L2 -> capacity thrash. Chunked
// swizzle pins each XCD to a contiguous m-range whose gather set is one
// 3.2MB batch slice (fits L2). No value-path change: only m0 is remapped via
// a proven-bijective formula (m204); per-lane b=m/N_ handles placement.

typedef __attribute__((ext_vector_type(8))) short bf16x8;
typedef __attribute__((ext_vector_type(4))) short s16x4;
typedef __attribute__((ext_vector_type(4))) float f32x4;
typedef __attribute__((ext_vector_type(4))) int   i32x4;

constexpr int B_ = 4, N_ = 50000, D_ = 32, K_ = 16, F_ = 32;
constexpr int M_ = B_ * N_;                      // 200000
constexpr int ROWS_PER_BLOCK = 64;               // 4 waves x 16 rows
constexpr int NWG = M_ / ROWS_PER_BLOCK;         // 3125 blocks

// ---- workspace layout (bytes) ----
constexpr size_t WSF_OFF = 0;                        // 32768 B  (B-fragments)
constexpr size_t X16_OFF = 32768;                    // 12,800,000 B (x bf16)
constexpr size_t NBR_OFF = X16_OFF + 12800000;       // 12,800,000 B (nbr i32)
constexpr size_t WS_NEED = NBR_OFF + 12800000;       // 25,632,768 B

__device__ __forceinline__ short f2bf_rne(float f) {
    union { float f; unsigned u; } v; v.f = f;
    unsigned r = v.u + 0x7FFFu + ((v.u >> 16) & 1u);
    return (short)(r >> 16);
}

// ================= fast path =================

__global__ __launch_bounds__(256) void prep_all(
    const float* __restrict__ x, const int* __restrict__ nbr,
    const float* __restrict__ kern,
    short* __restrict__ wsf, short* __restrict__ x16, int* __restrict__ nbr32)
{
    const int stride = gridDim.x * 256;
    const int t = blockIdx.x * 256 + threadIdx.x;

    // x: f32 -> bf16, vectorized 4-wide (1,600,000 vec4)
    const f32x4* x4 = (const f32x4*)x;
    s16x4* xo = (s16x4*)x16;
    for (int i = t; i < (B_ * N_ * D_) / 4; i += stride) {
        f32x4 v = x4[i];
        s16x4 o = { f2bf_rne(v.x), f2bf_rne(v.y), f2bf_rne(v.z), f2bf_rne(v.w) };
        xo[i] = o;
    }

    // nbr: int64-or-int32 -> dense int32 (200,000 vec4)
    const bool is64 = (nbr[1] | nbr[3] | nbr[5] | nbr[7] |
                       nbr[9] | nbr[11] | nbr[13] | nbr[15]) == 0;
    i32x4* nd = (i32x4*)nbr32;
    const i32x4* ns = (const i32x4*)nbr;
    if (is64) {
        for (int i = t; i < (N_ * K_) / 4; i += stride) {
            i32x4 a = ns[i * 2], c = ns[i * 2 + 1];
            nd[i] = (i32x4){a.x, a.z, c.x, c.z};
        }
    } else {
        for (int i = t; i < (N_ * K_) / 4; i += stride) nd[i] = ns[i];
    }

    // W -> wsf, verified fragment-coalesced layout:
    // wsf[((kk*2+h)*64 + lane)*8 + dd] = bf16(kern[kk][(lane>>4)*8+dd][h*16+(lane&15)])
    for (int e = t; e < K_ * D_ * F_; e += stride) {
        int kk = e >> 10, d = (e >> 5) & 31, f = e & 31;
        int h = f >> 4, lane = ((d >> 3) << 4) | (f & 15), dd = d & 7;
        wsf[(((kk * 2 + h) * 64) + lane) * 8 + dd] = f2bf_rne(kern[e]);
    }
}

__global__ __launch_bounds__(256) void graphconv_fast(
    const short* __restrict__ x16, const int* __restrict__ nbr32,
    const short* __restrict__ wsf, const float* __restrict__ bias,
    float* __restrict__ out)
{
    // identity image of wsf (16384 shorts = 32 KB); ds_read at slab+lane*16
    // is fully sequential per instruction -> LDS-peak, no conflicts.
    __shared__ __align__(16) short lb[K_ * 2 * 64 * 8];
    {
        const bf16x8* src = (const bf16x8*)wsf;
        bf16x8* dst = (bf16x8*)lb;
#pragma unroll
        for (int i = 0; i < 8; ++i)
            dst[threadIdx.x + i * 256] = src[threadIdx.x + i * 256];
    }
    __syncthreads();

    // bijective XCD-chunked swizzle (m204): q=390, rem=5 for NWG=3125.
    // XCD k (= bid%8) gets a contiguous chunk of block indices.
    const int bid = blockIdx.x;
    const int xcd = bid & 7;
    const int pos = bid >> 3;
    constexpr int q = NWG >> 3, rem = NWG & 7;   // 390, 5
    const int swz = (xcd < rem ? xcd * (q + 1)
                               : rem * (q + 1) + (xcd - rem) * q) + pos;

    const int lane  = threadIdx.x & 63;
    const int wid   = threadIdx.x >> 6;
    const int m0    = swz * ROWS_PER_BLOCK + wid * 16;
    const int r     = lane & 15;   // A-row / B-col this lane serves
    const int chunk = lane >> 4;   // 8-wide d-chunk
    const int m     = m0 + r;
    const int b     = m / N_;
    const int n     = m - b * N_;

    // all 16 indices in 4 vector loads
    const i32x4* ip = (const i32x4*)(nbr32 + (size_t)n * K_);
    i32x4 q0 = ip[0], q1 = ip[1], q2 = ip[2], q3 = ip[3];
    const int idxs[K_] = {q0.x, q0.y, q0.z, q0.w, q1.x, q1.y, q1.z, q1.w,
                          q2.x, q2.y, q2.z, q2.w, q3.x, q3.y, q3.z, q3.w};

    const short* xb = x16 + (size_t)b * (N_ * D_) + chunk * 8;
    const short* bf = lb + lane * 8;

    f32x4 acc0 = {0.f, 0.f, 0.f, 0.f};
    f32x4 acc1 = {0.f, 0.f, 0.f, 0.f};

#pragma unroll
    for (int kk = 0; kk < K_; ++kk) {
        bf16x8 a  = *reinterpret_cast<const bf16x8*>(xb + (size_t)idxs[kk] * D_);
        bf16x8 b0 = *reinterpret_cast<const bf16x8*>(bf + (kk * 2 + 0) * 512);
        bf16x8 b1 = *reinterpret_cast<const bf16x8*>(bf + (kk * 2 + 1) * 512);
        acc0 = __builtin_amdgcn_mfma_f32_16x16x32_bf16(a, b0, acc0, 0, 0, 0);
        acc1 = __builtin_amdgcn_mfma_f32_16x16x32_bf16(a, b1, acc1, 0, 0, 0);
    }

    // epilogue (verified): C col = lane&15, row = (lane>>4)*4 + j
    const float bv0 = bias[r];
    const float bv1 = bias[16 + r];
    const int rowbase = m0 + chunk * 4;
#pragma unroll
    for (int j = 0; j < 4; ++j) {
        const size_t o = (size_t)(rowbase + j) * F_;
        float v0 = acc0[j] + bv0;
        float v1 = acc1[j] + bv1;
        out[o + r]      = v0 > 0.f ? v0 : 0.f;
        out[o + 16 + r] = v1 > 0.f ? v1 : 0.f;
    }
}

// ================= fallback path (verified round-8, needs only 40KB ws) =====

constexpr int DPAD = 40;
constexpr int KSTRIDE = F_ * DPAD;               // 1280 shorts per k-slab

__global__ __launch_bounds__(256) void prep_w8(const float* __restrict__ kern,
                                               short* __restrict__ ws16) {
    int e = blockIdx.x * 256 + threadIdx.x;
    int kk = e >> 10, d = (e >> 5) & 31, f = e & 31;
    ws16[kk * KSTRIDE + f * DPAD + d] = f2bf_rne(kern[e]);
}

__global__ __launch_bounds__(256) void graphconv_mfma8(
    const float* __restrict__ x, const int* __restrict__ nbr,
    const short* __restrict__ ws16, const float* __restrict__ bias,
    float* __restrict__ out)
{
    const bool is64 = (nbr[1] | nbr[3] | nbr[5] | nbr[7] |
                       nbr[9] | nbr[11] | nbr[13] | nbr[15]) == 0;
    const int istride = is64 ? 2 : 1;

    const int lane = threadIdx.x & 63;
    const int wid  = threadIdx.x >> 6;
    const int m0   = blockIdx.x * ROWS_PER_BLOCK + wid * 16;
    const int r = lane & 15, chunk = lane >> 4;
    const int m = m0 + r;
    const int b = m / N_;
    const int n = m - b * N_;

    int idxs[K_];
#pragma unroll
    for (int kk = 0; kk < K_; ++kk)
        idxs[kk] = nbr[(size_t)(n * K_ + kk) * istride];

    const float* xbase = x + (size_t)b * (N_ * D_) + chunk * 8;
    const short* bcol0 = ws16 + r * DPAD + chunk * 8;
    const short* bcol1 = ws16 + (16 + r) * DPAD + chunk * 8;

    f32x4 acc0 = {0.f, 0.f, 0.f, 0.f};
    f32x4 acc1 = {0.f, 0.f, 0.f, 0.f};

#pragma unroll
    for (int kk = 0; kk < K_; ++kk) {
        const float* xr = xbase + (size_t)idxs[kk] * D_;
        f32x4 xa = *reinterpret_cast<const f32x4*>(xr);
        f32x4 xb = *reinterpret_cast<const f32x4*>(xr + 4);
        unsigned p0, p1, p2, p3;
        asm("v_cvt_pk_bf16_f32 %0, %1, %2" : "=v"(p0) : "v"(xa.x), "v"(xa.y));
        asm("v_cvt_pk_bf16_f32 %0, %1, %2" : "=v"(p1) : "v"(xa.z), "v"(xa.w));
        asm("v_cvt_pk_bf16_f32 %0, %1, %2" : "=v"(p2) : "v"(xb.x), "v"(xb.y));
        asm("v_cvt_pk_bf16_f32 %0, %1, %2" : "=v"(p3) : "v"(xb.z), "v"(xb.w));
        union { unsigned u[4]; bf16x8 v; } af;
        af.u[0] = p0; af.u[1] = p1; af.u[2] = p2; af.u[3] = p3;
        bf16x8 b0 = *reinterpret_cast<const bf16x8*>(bcol0 + kk * KSTRIDE);
        bf16x8 b1 = *reinterpret_cast<const bf16x8*>(bcol1 + kk * KSTRIDE);
        acc0 = __builtin_amdgcn_mfma_f32_16x16x32_bf16(af.v, b0, acc0, 0, 0, 0);
        acc1 = __builtin_amdgcn_mfma_f32_16x16x32_bf16(af.v, b1, acc1, 0, 0, 0);
    }

    const float bv0 = bias[r];
    const float bv1 = bias[16 + r];
    const int rowbase = m0 + chunk * 4;
#pragma unroll
    for (int j = 0; j < 4; ++j) {
        const size_t o = (size_t)(rowbase + j) * F_;
        float v0 = acc0[j] + bv0;
        float v1 = acc1[j] + bv1;
        out[o + r]      = v0 > 0.f ? v0 : 0.f;
        out[o + 16 + r] = v1 > 0.f ? v1 : 0.f;
    }
}

// ================= launch =================

extern "C" void kernel_launch(void* const* d_in, const int* in_sizes, int n_in,
                              void* d_out, int out_size, void* d_ws, size_t ws_size,
                              hipStream_t stream) {
    const float* x    = (const float*)d_in[0];
    const int*   nbr  = (const int*)d_in[1];
    const float* kern = (const float*)d_in[2];
    const float* bias = (const float*)d_in[3];
    float* out = (float*)d_out;

    if (ws_size >= WS_NEED) {
        char* ws = (char*)d_ws;
        short* wsf   = (short*)(ws + WSF_OFF);
        short* x16   = (short*)(ws + X16_OFF);
        int*   nbr32 = (int*)(ws + NBR_OFF);
        prep_all<<<dim3(1024), 256, 0, stream>>>(x, nbr, kern, wsf, x16, nbr32);
        graphconv_fast<<<dim3(NWG), 256, 0, stream>>>(
            x16, nbr32, wsf, bias, out);
    } else {
        short* ws16 = (short*)d_ws;   // 40960 B
        prep_w8<<<dim3(K_ * D_ * F_ / 256), 256, 0, stream>>>(kern, ws16);
        graphconv_mfma8<<<dim3(NWG), 256, 0, stream>>>(
            x, nbr, ws16, bias, out);
    }
}

// Round 13
// 43.127 us; speedup vs baseline: 2.1486x; 1.0228x over previous
//
#include <hip/hip_runtime.h>
#include <hip/hip_bf16.h>

// GraphConv: out[b,n,f] = relu( sum_{k,d} x[b, nbr[n,k], d] * W[k,d,f] + bias[f] )
// B=4, N=50000, D=32, K=16, F=32.  M = B*N = 200000 rows, contraction = 512.
//
// Round 12 = round 11 (PASS, 45.0us) + ONE change: bijective XCD-chunked
// block swizzle. Theory: in-flight blocks (~40% of grid) span ~2 batches per
// XCD -> gather working set ~6.4MB > 4MiB XCD-L2 -> capacity thrash. Chunked
// swizzle pins each XCD to a contiguous m-range whose gather set is one
// 3.2MB batch slice (fits L2). No value-path change: only m0 is remapped via
// a proven-bijective formula (m204); per-lane b=m/N_ handles placement.

typedef __attribute__((ext_vector_type(8))) short bf16x8;
typedef __attribute__((ext_vector_type(4))) short s16x4;
typedef __attribute__((ext_vector_type(4))) float f32x4;
typedef __attribute__((ext_vector_type(4))) int   i32x4;

constexpr int B_ = 4, N_ = 50000, D_ = 32, K_ = 16, F_ = 32;
constexpr int M_ = B_ * N_;                      // 200000
constexpr int ROWS_PER_BLOCK = 64;               // 4 waves x 16 rows
constexpr int NWG = M_ / ROWS_PER_BLOCK;         // 3125 blocks

// ---- workspace layout (bytes) ----
constexpr size_t WSF_OFF = 0;                        // 32768 B  (B-fragments)
constexpr size_t X16_OFF = 32768;                    // 12,800,000 B (x bf16)
constexpr size_t NBR_OFF = X16_OFF + 12800000;       // 12,800,000 B (nbr i32)
constexpr size_t WS_NEED = NBR_OFF + 12800000;       // 25,632,768 B

__device__ __forceinline__ short f2bf_rne(float f) {
    union { float f; unsigned u; } v; v.f = f;
    unsigned r = v.u + 0x7FFFu + ((v.u >> 16) & 1u);
    return (short)(r >> 16);
}

// ================= fast path =================

__global__ __launch_bounds__(256) void prep_all(
    const float* __restrict__ x, const int* __restrict__ nbr,
    const float* __restrict__ kern,
    short* __restrict__ wsf, short* __restrict__ x16, int* __restrict__ nbr32)
{
    const int stride = gridDim.x * 256;
    const int t = blockIdx.x * 256 + threadIdx.x;

    // x: f32 -> bf16, vectorized 4-wide (1,600,000 vec4)
    const f32x4* x4 = (const f32x4*)x;
    s16x4* xo = (s16x4*)x16;
    for (int i = t; i < (B_ * N_ * D_) / 4; i += stride) {
        f32x4 v = x4[i];
        s16x4 o = { f2bf_rne(v.x), f2bf_rne(v.y), f2bf_rne(v.z), f2bf_rne(v.w) };
        xo[i] = o;
    }

    // nbr: int64-or-int32 -> dense int32 (200,000 vec4)
    const bool is64 = (nbr[1] | nbr[3] | nbr[5] | nbr[7] |
                       nbr[9] | nbr[11] | nbr[13] | nbr[15]) == 0;
    i32x4* nd = (i32x4*)nbr32;
    const i32x4* ns = (const i32x4*)nbr;
    if (is64) {
        for (int i = t; i < (N_ * K_) / 4; i += stride) {
            i32x4 a = ns[i * 2], c = ns[i * 2 + 1];
            nd[i] = (i32x4){a.x, a.z, c.x, c.z};
        }
    } else {
        for (int i = t; i < (N_ * K_) / 4; i += stride) nd[i] = ns[i];
    }

    // W -> wsf, verified fragment-coalesced layout:
    // wsf[((kk*2+h)*64 + lane)*8 + dd] = bf16(kern[kk][(lane>>4)*8+dd][h*16+(lane&15)])
    for (int e = t; e < K_ * D_ * F_; e += stride) {
        int kk = e >> 10, d = (e >> 5) & 31, f = e & 31;
        int h = f >> 4, lane = ((d >> 3) << 4) | (f & 15), dd = d & 7;
        wsf[(((kk * 2 + h) * 64) + lane) * 8 + dd] = f2bf_rne(kern[e]);
    }
}

__global__ __launch_bounds__(256) void graphconv_fast(
    const short* __restrict__ x16, const int* __restrict__ nbr32,
    const short* __restrict__ wsf, const float* __restrict__ bias,
    float* __restrict__ out)
{
    // identity image of wsf (16384 shorts = 32 KB); ds_read at slab+lane*16
    // is fully sequential per instruction -> LDS-peak, no conflicts.
    __shared__ __align__(16) short lb[K_ * 2 * 64 * 8];
    {
        const bf16x8* src = (const bf16x8*)wsf;
        bf16x8* dst = (bf16x8*)lb;
#pragma unroll
        for (int i = 0; i < 8; ++i)
            dst[threadIdx.x + i * 256] = src[threadIdx.x + i * 256];
    }
    __syncthreads();

    // bijective XCD-chunked swizzle (m204): q=390, rem=5 for NWG=3125.
    // XCD k (= bid%8) gets a contiguous chunk of block indices.
    const int bid = blockIdx.x;
    const int xcd = bid & 7;
    const int pos = bid >> 3;
    constexpr int q = NWG >> 3, rem = NWG & 7;   // 390, 5
    const int swz = (xcd < rem ? xcd * (q + 1)
                               : rem * (q + 1) + (xcd - rem) * q) + pos;

    const int lane  = threadIdx.x & 63;
    const int wid   = threadIdx.x >> 6;
    const int m0    = swz * ROWS_PER_BLOCK + wid * 16;
    const int r     = lane & 15;   // A-row / B-col this lane serves
    const int chunk = lane >> 4;   // 8-wide d-chunk
    const int m     = m0 + r;
    const int b     = m / N_;
    const int n     = m - b * N_;

    // all 16 indices in 4 vector loads
    const i32x4* ip = (const i32x4*)(nbr32 + (size_t)n * K_);
    i32x4 q0 = ip[0], q1 = ip[1], q2 = ip[2], q3 = ip[3];
    const int idxs[K_] = {q0.x, q0.y, q0.z, q0.w, q1.x, q1.y, q1.z, q1.w,
                          q2.x, q2.y, q2.z, q2.w, q3.x, q3.y, q3.z, q3.w};

    const short* xb = x16 + (size_t)b * (N_ * D_) + chunk * 8;
    const short* bf = lb + lane * 8;

    f32x4 acc0 = {0.f, 0.f, 0.f, 0.f};
    f32x4 acc1 = {0.f, 0.f, 0.f, 0.f};

#pragma unroll
    for (int kk = 0; kk < K_; ++kk) {
        bf16x8 a  = *reinterpret_cast<const bf16x8*>(xb + (size_t)idxs[kk] * D_);
        bf16x8 b0 = *reinterpret_cast<const bf16x8*>(bf + (kk * 2 + 0) * 512);
        bf16x8 b1 = *reinterpret_cast<const bf16x8*>(bf + (kk * 2 + 1) * 512);
        acc0 = __builtin_amdgcn_mfma_f32_16x16x32_bf16(a, b0, acc0, 0, 0, 0);
        acc1 = __builtin_amdgcn_mfma_f32_16x16x32_bf16(a, b1, acc1, 0, 0, 0);
    }

    // epilogue (verified): C col = lane&15, row = (lane>>4)*4 + j
    const float bv0 = bias[r];
    const float bv1 = bias[16 + r];
    const int rowbase = m0 + chunk * 4;
#pragma unroll
    for (int j = 0; j < 4; ++j) {
        const size_t o = (size_t)(rowbase + j) * F_;
        float v0 = acc0[j] + bv0;
        float v1 = acc1[j] + bv1;
        out[o + r]      = v0 > 0.f ? v0 : 0.f;
        out[o + 16 + r] = v1 > 0.f ? v1 : 0.f;
    }
}

// ================= fallback path (verified round-8, needs only 40KB ws) =====

constexpr int DPAD = 40;
constexpr int KSTRIDE = F_ * DPAD;               // 1280 shorts per k-slab

__global__ __launch_bounds__(256) void prep_w8(const float* __restrict__ kern,
                                               short* __restrict__ ws16) {
    int e = blockIdx.x * 256 + threadIdx.x;
    int kk = e >> 10, d = (e >> 5) & 31, f = e & 31;
    ws16[kk * KSTRIDE + f * DPAD + d] = f2bf_rne(kern[e]);
}

__global__ __launch_bounds__(256) void graphconv_mfma8(
    const float* __restrict__ x, const int* __restrict__ nbr,
    const short* __restrict__ ws16, const float* __restrict__ bias,
    float* __restrict__ out)
{
    const bool is64 = (nbr[1] | nbr[3] | nbr[5] | nbr[7] |
                       nbr[9] | nbr[11] | nbr[13] | nbr[15]) == 0;
    const int istride = is64 ? 2 : 1;

    const int lane = threadIdx.x & 63;
    const int wid  = threadIdx.x >> 6;
    const int m0   = blockIdx.x * ROWS_PER_BLOCK + wid * 16;
    const int r = lane & 15, chunk = lane >> 4;
    const int m = m0 + r;
    const int b = m / N_;
    const int n = m - b * N_;

    int idxs[K_];
#pragma unroll
    for (int kk = 0; kk < K_; ++kk)
        idxs[kk] = nbr[(size_t)(n * K_ + kk) * istride];

    const float* xbase = x + (size_t)b * (N_ * D_) + chunk * 8;
    const short* bcol0 = ws16 + r * DPAD + chunk * 8;
    const short* bcol1 = ws16 + (16 + r) * DPAD + chunk * 8;

    f32x4 acc0 = {0.f, 0.f, 0.f, 0.f};
    f32x4 acc1 = {0.f, 0.f, 0.f, 0.f};

#pragma unroll
    for (int kk = 0; kk < K_; ++kk) {
        const float* xr = xbase + (size_t)idxs[kk] * D_;
        f32x4 xa = *reinterpret_cast<const f32x4*>(xr);
        f32x4 xb = *reinterpret_cast<const f32x4*>(xr + 4);
        unsigned p0, p1, p2, p3;
        asm("v_cvt_pk_bf16_f32 %0, %1, %2" : "=v"(p0) : "v"(xa.x), "v"(xa.y));
        asm("v_cvt_pk_bf16_f32 %0, %1, %2" : "=v"(p1) : "v"(xa.z), "v"(xa.w));
        asm("v_cvt_pk_bf16_f32 %0, %1, %2" : "=v"(p2) : "v"(xb.x), "v"(xb.y));
        asm("v_cvt_pk_bf16_f32 %0, %1, %2" : "=v"(p3) : "v"(xb.z), "v"(xb.w));
        union { unsigned u[4]; bf16x8 v; } af;
        af.u[0] = p0; af.u[1] = p1; af.u[2] = p2; af.u[3] = p3;
        bf16x8 b0 = *reinterpret_cast<const bf16x8*>(bcol0 + kk * KSTRIDE);
        bf16x8 b1 = *reinterpret_cast<const bf16x8*>(bcol1 + kk * KSTRIDE);
        acc0 = __builtin_amdgcn_mfma_f32_16x16x32_bf16(af.v, b0, acc0, 0, 0, 0);
        acc1 = __builtin_amdgcn_mfma_f32_16x16x32_bf16(af.v, b1, acc1, 0, 0, 0);
    }

    const float bv0 = bias[r];
    const float bv1 = bias[16 + r];
    const int rowbase = m0 + chunk * 4;
#pragma unroll
    for (int j = 0; j < 4; ++j) {
        const size_t o = (size_t)(rowbase + j) * F_;
        float v0 = acc0[j] + bv0;
        float v1 = acc1[j] + bv1;
        out[o + r]      = v0 > 0.f ? v0 : 0.f;
        out[o + 16 + r] = v1 > 0.f ? v1 : 0.f;
    }
}

// ================= launch =================

extern "C" void kernel_launch(void* const* d_in, const int* in_sizes, int n_in,
                              void* d_out, int out_size, void* d_ws, size_t ws_size,
                              hipStream_t stream) {
    const float* x    = (const float*)d_in[0];
    const int*   nbr  = (const int*)d_in[1];
    const float* kern = (const float*)d_in[2];
    const float* bias = (const float*)d_in[3];
    float* out = (float*)d_out;

    if (ws_size >= WS_NEED) {
        char* ws = (char*)d_ws;
        short* wsf   = (short*)(ws + WSF_OFF);
        short* x16   = (short*)(ws + X16_OFF);
        int*   nbr32 = (int*)(ws + NBR_OFF);
        prep_all<<<dim3(1024), 256, 0, stream>>>(x, nbr, kern, wsf, x16, nbr32);
        graphconv_fast<<<dim3(NWG), 256, 0, stream>>>(
            x16, nbr32, wsf, bias, out);
    } else {
        short* ws16 = (short*)d_ws;   // 40960 B
        prep_w8<<<dim3(K_ * D_ * F_ / 256), 256, 0, stream>>>(kern, ws16);
        graphconv_mfma8<<<dim3(NWG), 256, 0, stream>>>(
            x, nbr, ws16, bias, out);
    }
}

// Round 14
// 42.105 us; speedup vs baseline: 2.2007x; 1.0243x over previous
//
#include <hip/hip_runtime.h>
#include <hip/hip_bf16.h>

// GraphConv: out[b,n,f] = relu( sum_{k,d} x[b, nbr[n,k], d] * W[k,d,f] + bias[f] )
// B=4, N=50000, D=32, K=16, F=32.  M = B*N = 200000 rows, contraction = 512.
//
// Round 14 = round 13 (PASS, 43.1us) + ONE change: drop the nbr32 compaction
// pass. Main reads the int64 neighbor buffer directly (8x i32x4 stride-2
// loads, idx[2v]=q.x idx[2v+1]=q.z). Saves 38.4MB of prep traffic (~6.5us);
// costs +4 idx instrs/wave in main (~1.5%). All other code byte-identical
// to the verified round-13 kernel (x16 conversion, wsf layout, LDS identity
// copy, XCD swizzle, epilogue).

typedef __attribute__((ext_vector_type(8))) short bf16x8;
typedef __attribute__((ext_vector_type(4))) short s16x4;
typedef __attribute__((ext_vector_type(4))) float f32x4;
typedef __attribute__((ext_vector_type(4))) int   i32x4;

constexpr int B_ = 4, N_ = 50000, D_ = 32, K_ = 16, F_ = 32;
constexpr int M_ = B_ * N_;                      // 200000
constexpr int ROWS_PER_BLOCK = 64;               // 4 waves x 16 rows
constexpr int NWG = M_ / ROWS_PER_BLOCK;         // 3125 blocks

// ---- workspace layout (bytes) ----
constexpr size_t WSF_OFF = 0;                        // 32768 B  (B-fragments)
constexpr size_t X16_OFF = 32768;                    // 12,800,000 B (x bf16)
constexpr size_t WS_NEED = X16_OFF + 12800000;       // 12,832,768 B

__device__ __forceinline__ short f2bf_rne(float f) {
    union { float f; unsigned u; } v; v.f = f;
    unsigned r = v.u + 0x7FFFu + ((v.u >> 16) & 1u);
    return (short)(r >> 16);
}

// ================= fast path =================

__global__ __launch_bounds__(256) void prep_all(
    const float* __restrict__ x, const float* __restrict__ kern,
    short* __restrict__ wsf, short* __restrict__ x16)
{
    const int stride = gridDim.x * 256;
    const int t = blockIdx.x * 256 + threadIdx.x;

    // x: f32 -> bf16, vectorized 4-wide (1,600,000 vec4)
    const f32x4* x4 = (const f32x4*)x;
    s16x4* xo = (s16x4*)x16;
    for (int i = t; i < (B_ * N_ * D_) / 4; i += stride) {
        f32x4 v = x4[i];
        s16x4 o = { f2bf_rne(v.x), f2bf_rne(v.y), f2bf_rne(v.z), f2bf_rne(v.w) };
        xo[i] = o;
    }

    // W -> wsf, verified fragment-coalesced layout:
    // wsf[((kk*2+h)*64 + lane)*8 + dd] = bf16(kern[kk][(lane>>4)*8+dd][h*16+(lane&15)])
    for (int e = t; e < K_ * D_ * F_; e += stride) {
        int kk = e >> 10, d = (e >> 5) & 31, f = e & 31;
        int h = f >> 4, lane = ((d >> 3) << 4) | (f & 15), dd = d & 7;
        wsf[(((kk * 2 + h) * 64) + lane) * 8 + dd] = f2bf_rne(kern[e]);
    }
}

__global__ __launch_bounds__(256) void graphconv_fast(
    const short* __restrict__ x16, const int* __restrict__ nbr,
    const short* __restrict__ wsf, const float* __restrict__ bias,
    float* __restrict__ out)
{
    // identity image of wsf (16384 shorts = 32 KB); ds_read at slab+lane*16
    // is fully sequential per instruction -> LDS-peak, no conflicts.
    __shared__ __align__(16) short lb[K_ * 2 * 64 * 8];
    {
        const bf16x8* src = (const bf16x8*)wsf;
        bf16x8* dst = (bf16x8*)lb;
#pragma unroll
        for (int i = 0; i < 8; ++i)
            dst[threadIdx.x + i * 256] = src[threadIdx.x + i * 256];
    }
    __syncthreads();

    // bijective XCD-chunked swizzle (m204): q=390, rem=5 for NWG=3125.
    const int bid = blockIdx.x;
    const int xcd = bid & 7;
    const int pos = bid >> 3;
    constexpr int q = NWG >> 3, rem = NWG & 7;   // 390, 5
    const int swz = (xcd < rem ? xcd * (q + 1)
                               : rem * (q + 1) + (xcd - rem) * q) + pos;

    const int lane  = threadIdx.x & 63;
    const int wid   = threadIdx.x >> 6;
    const int m0    = swz * ROWS_PER_BLOCK + wid * 16;
    const int r     = lane & 15;   // A-row / B-col this lane serves
    const int chunk = lane >> 4;   // 8-wide d-chunk
    const int m     = m0 + r;
    const int b     = m / N_;
    const int n     = m - b * N_;

    // int64-pushed-as-int32 detection (odd dwords are zero high words).
    const bool is64 = (nbr[1] | nbr[3] | nbr[5] | nbr[7] |
                       nbr[9] | nbr[11] | nbr[13] | nbr[15]) == 0;

    // 16 indices, read directly from the input buffer (uniform branch).
    int idxs[K_];
    if (is64) {
        // int64 little-endian: value dword at even index -> q.x, q.z
        const i32x4* ip = (const i32x4*)(nbr + (size_t)n * K_ * 2);
#pragma unroll
        for (int v = 0; v < 8; ++v) {
            i32x4 qv = ip[v];
            idxs[v * 2]     = qv.x;
            idxs[v * 2 + 1] = qv.z;
        }
    } else {
        const i32x4* ip = (const i32x4*)(nbr + (size_t)n * K_);
#pragma unroll
        for (int v = 0; v < 4; ++v) {
            i32x4 qv = ip[v];
            idxs[v * 4]     = qv.x;
            idxs[v * 4 + 1] = qv.y;
            idxs[v * 4 + 2] = qv.z;
            idxs[v * 4 + 3] = qv.w;
        }
    }

    const short* xb = x16 + (size_t)b * (N_ * D_) + chunk * 8;
    const short* bf = lb + lane * 8;

    f32x4 acc0 = {0.f, 0.f, 0.f, 0.f};
    f32x4 acc1 = {0.f, 0.f, 0.f, 0.f};

#pragma unroll
    for (int kk = 0; kk < K_; ++kk) {
        bf16x8 a  = *reinterpret_cast<const bf16x8*>(xb + (size_t)idxs[kk] * D_);
        bf16x8 b0 = *reinterpret_cast<const bf16x8*>(bf + (kk * 2 + 0) * 512);
        bf16x8 b1 = *reinterpret_cast<const bf16x8*>(bf + (kk * 2 + 1) * 512);
        acc0 = __builtin_amdgcn_mfma_f32_16x16x32_bf16(a, b0, acc0, 0, 0, 0);
        acc1 = __builtin_amdgcn_mfma_f32_16x16x32_bf16(a, b1, acc1, 0, 0, 0);
    }

    // epilogue (verified): C col = lane&15, row = (lane>>4)*4 + j
    const float bv0 = bias[r];
    const float bv1 = bias[16 + r];
    const int rowbase = m0 + chunk * 4;
#pragma unroll
    for (int j = 0; j < 4; ++j) {
        const size_t o = (size_t)(rowbase + j) * F_;
        float v0 = acc0[j] + bv0;
        float v1 = acc1[j] + bv1;
        out[o + r]      = v0 > 0.f ? v0 : 0.f;
        out[o + 16 + r] = v1 > 0.f ? v1 : 0.f;
    }
}

// ================= fallback path (verified round-8, needs only 40KB ws) =====

constexpr int DPAD = 40;
constexpr int KSTRIDE = F_ * DPAD;               // 1280 shorts per k-slab

__global__ __launch_bounds__(256) void prep_w8(const float* __restrict__ kern,
                                               short* __restrict__ ws16) {
    int e = blockIdx.x * 256 + threadIdx.x;
    int kk = e >> 10, d = (e >> 5) & 31, f = e & 31;
    ws16[kk * KSTRIDE + f * DPAD + d] = f2bf_rne(kern[e]);
}

__global__ __launch_bounds__(256) void graphconv_mfma8(
    const float* __restrict__ x, const int* __restrict__ nbr,
    const short* __restrict__ ws16, const float* __restrict__ bias,
    float* __restrict__ out)
{
    const bool is64 = (nbr[1] | nbr[3] | nbr[5] | nbr[7] |
                       nbr[9] | nbr[11] | nbr[13] | nbr[15]) == 0;
    const int istride = is64 ? 2 : 1;

    const int lane = threadIdx.x & 63;
    const int wid  = threadIdx.x >> 6;
    const int m0   = blockIdx.x * ROWS_PER_BLOCK + wid * 16;
    const int r = lane & 15, chunk = lane >> 4;
    const int m = m0 + r;
    const int b = m / N_;
    const int n = m - b * N_;

    int idxs[K_];
#pragma unroll
    for (int kk = 0; kk < K_; ++kk)
        idxs[kk] = nbr[(size_t)(n * K_ + kk) * istride];

    const float* xbase = x + (size_t)b * (N_ * D_) + chunk * 8;
    const short* bcol0 = ws16 + r * DPAD + chunk * 8;
    const short* bcol1 = ws16 + (16 + r) * DPAD + chunk * 8;

    f32x4 acc0 = {0.f, 0.f, 0.f, 0.f};
    f32x4 acc1 = {0.f, 0.f, 0.f, 0.f};

#pragma unroll
    for (int kk = 0; kk < K_; ++kk) {
        const float* xr = xbase + (size_t)idxs[kk] * D_;
        f32x4 xa = *reinterpret_cast<const f32x4*>(xr);
        f32x4 xb = *reinterpret_cast<const f32x4*>(xr + 4);
        unsigned p0, p1, p2, p3;
        asm("v_cvt_pk_bf16_f32 %0, %1, %2" : "=v"(p0) : "v"(xa.x), "v"(xa.y));
        asm("v_cvt_pk_bf16_f32 %0, %1, %2" : "=v"(p1) : "v"(xa.z), "v"(xa.w));
        asm("v_cvt_pk_bf16_f32 %0, %1, %2" : "=v"(p2) : "v"(xb.x), "v"(xb.y));
        asm("v_cvt_pk_bf16_f32 %0, %1, %2" : "=v"(p3) : "v"(xb.z), "v"(xb.w));
        union { unsigned u[4]; bf16x8 v; } af;
        af.u[0] = p0; af.u[1] = p1; af.u[2] = p2; af.u[3] = p3;
        bf16x8 b0 = *reinterpret_cast<const bf16x8*>(bcol0 + kk * KSTRIDE);
        bf16x8 b1 = *reinterpret_cast<const bf16x8*>(bcol1 + kk * KSTRIDE);
        acc0 = __builtin_amdgcn_mfma_f32_16x16x32_bf16(af.v, b0, acc0, 0, 0, 0);
        acc1 = __builtin_amdgcn_mfma_f32_16x16x32_bf16(af.v, b1, acc1, 0, 0, 0);
    }

    const float bv0 = bias[r];
    const float bv1 = bias[16 + r];
    const int rowbase = m0 + chunk * 4;
#pragma unroll
    for (int j = 0; j < 4; ++j) {
        const size_t o = (size_t)(rowbase + j) * F_;
        float v0 = acc0[j] + bv0;
        float v1 = acc1[j] + bv1;
        out[o + r]      = v0 > 0.f ? v0 : 0.f;
        out[o + 16 + r] = v1 > 0.f ? v1 : 0.f;
    }
}

// ================= launch =================

extern "C" void kernel_launch(void* const* d_in, const int* in_sizes, int n_in,
                              void* d_out, int out_size, void* d_ws, size_t ws_size,
                              hipStream_t stream) {
    const float* x    = (const float*)d_in[0];
    const int*   nbr  = (const int*)d_in[1];
    const float* kern = (const float*)d_in[2];
    const float* bias = (const float*)d_in[3];
    float* out = (float*)d_out;

    if (ws_size >= WS_NEED) {
        char* ws = (char*)d_ws;
        short* wsf = (short*)(ws + WSF_OFF);
        short* x16 = (short*)(ws + X16_OFF);
        prep_all<<<dim3(1024), 256, 0, stream>>>(x, kern, wsf, x16);
        graphconv_fast<<<dim3(NWG), 256, 0, stream>>>(
            x16, nbr, wsf, bias, out);
    } else {
        short* ws16 = (short*)d_ws;   // 40960 B
        prep_w8<<<dim3(K_ * D_ * F_ / 256), 256, 0, stream>>>(kern, ws16);
        graphconv_mfma8<<<dim3(NWG), 256, 0, stream>>>(
            x, nbr, ws16, bias, out);
    }
}

// Round 15
// 41.938 us; speedup vs baseline: 2.2094x; 1.0040x over previous
//
#include <hip/hip_runtime.h>
#include <hip/hip_bf16.h>

// GraphConv: out[b,n,f] = relu( sum_{k,d} x[b, nbr[n,k], d] * W[k,d,f] + bias[f] )
// B=4, N=50000, D=32, K=16, F=32.  M = B*N = 200000 rows, contraction = 512.
//
// Round 15 = round 14 (PASS, 42.1us) + ONE change: u16 index compaction.
// Indices < 50000 < 2^16. Prep packs nbr (int64-or-int32) to u16 (6.4MB);
// main reads each row's 16 indices as 2x u16x8 (16 lines/wave vs 128 for
// direct int64). Line-count model (confirmed by r13->r14 delta: 64 lines/wave
// ~ 5us): main -7us, prep +5.3us. Unpack = ushort vector element -> int
// (implicit zero-extend). All else byte-identical to the r14 PASS.

typedef __attribute__((ext_vector_type(8))) short bf16x8;
typedef __attribute__((ext_vector_type(8))) unsigned short u16x8;
typedef __attribute__((ext_vector_type(4))) short s16x4;
typedef __attribute__((ext_vector_type(4))) float f32x4;
typedef __attribute__((ext_vector_type(4))) int   i32x4;

constexpr int B_ = 4, N_ = 50000, D_ = 32, K_ = 16, F_ = 32;
constexpr int M_ = B_ * N_;                      // 200000
constexpr int ROWS_PER_BLOCK = 64;               // 4 waves x 16 rows
constexpr int NWG = M_ / ROWS_PER_BLOCK;         // 3125 blocks

// ---- workspace layout (bytes) ----
constexpr size_t WSF_OFF = 0;                        // 32768 B  (B-fragments)
constexpr size_t X16_OFF = 32768;                    // 12,800,000 B (x bf16)
constexpr size_t N16_OFF = X16_OFF + 12800000;       // 6,400,000 B (nbr u16)
constexpr size_t WS_NEED = N16_OFF + 6400000;        // 19,232,768 B

__device__ __forceinline__ short f2bf_rne(float f) {
    union { float f; unsigned u; } v; v.f = f;
    unsigned r = v.u + 0x7FFFu + ((v.u >> 16) & 1u);
    return (short)(r >> 16);
}

// ================= fast path =================

__global__ __launch_bounds__(256) void prep_all(
    const float* __restrict__ x, const int* __restrict__ nbr,
    const float* __restrict__ kern,
    short* __restrict__ wsf, short* __restrict__ x16,
    unsigned short* __restrict__ nbr16)
{
    const int stride = gridDim.x * 256;
    const int t = blockIdx.x * 256 + threadIdx.x;

    // x: f32 -> bf16, vectorized 4-wide (1,600,000 vec4)
    const f32x4* x4 = (const f32x4*)x;
    s16x4* xo = (s16x4*)x16;
    for (int i = t; i < (B_ * N_ * D_) / 4; i += stride) {
        f32x4 v = x4[i];
        s16x4 o = { f2bf_rne(v.x), f2bf_rne(v.y), f2bf_rne(v.z), f2bf_rne(v.w) };
        xo[i] = o;
    }

    // nbr -> u16 (indices < 50000 < 2^16). int64-or-int32 handled uniformly.
    const bool is64 = (nbr[1] | nbr[3] | nbr[5] | nbr[7] |
                       nbr[9] | nbr[11] | nbr[13] | nbr[15]) == 0;
    if (is64) {
        for (int i = t; i < N_ * K_; i += stride)
            nbr16[i] = (unsigned short)nbr[(size_t)i * 2];
    } else {
        for (int i = t; i < N_ * K_; i += stride)
            nbr16[i] = (unsigned short)nbr[i];
    }

    // W -> wsf, verified fragment-coalesced layout:
    // wsf[((kk*2+h)*64 + lane)*8 + dd] = bf16(kern[kk][(lane>>4)*8+dd][h*16+(lane&15)])
    for (int e = t; e < K_ * D_ * F_; e += stride) {
        int kk = e >> 10, d = (e >> 5) & 31, f = e & 31;
        int h = f >> 4, lane = ((d >> 3) << 4) | (f & 15), dd = d & 7;
        wsf[(((kk * 2 + h) * 64) + lane) * 8 + dd] = f2bf_rne(kern[e]);
    }
}

__global__ __launch_bounds__(256) void graphconv_fast(
    const short* __restrict__ x16, const unsigned short* __restrict__ nbr16,
    const short* __restrict__ wsf, const float* __restrict__ bias,
    float* __restrict__ out)
{
    // identity image of wsf (16384 shorts = 32 KB); ds_read at slab+lane*16
    // is fully sequential per instruction -> LDS-peak, no conflicts.
    __shared__ __align__(16) short lb[K_ * 2 * 64 * 8];
    {
        const bf16x8* src = (const bf16x8*)wsf;
        bf16x8* dst = (bf16x8*)lb;
#pragma unroll
        for (int i = 0; i < 8; ++i)
            dst[threadIdx.x + i * 256] = src[threadIdx.x + i * 256];
    }
    __syncthreads();

    // bijective XCD-chunked swizzle (m204): q=390, rem=5 for NWG=3125.
    const int bid = blockIdx.x;
    const int xcd = bid & 7;
    const int pos = bid >> 3;
    constexpr int q = NWG >> 3, rem = NWG & 7;   // 390, 5
    const int swz = (xcd < rem ? xcd * (q + 1)
                               : rem * (q + 1) + (xcd - rem) * q) + pos;

    const int lane  = threadIdx.x & 63;
    const int wid   = threadIdx.x >> 6;
    const int m0    = swz * ROWS_PER_BLOCK + wid * 16;
    const int r     = lane & 15;   // A-row / B-col this lane serves
    const int chunk = lane >> 4;   // 8-wide d-chunk
    const int m     = m0 + r;
    const int b     = m / N_;
    const int n     = m - b * N_;

    // 16 indices in 2 vector loads (row stream = 32B; 16 consecutive rows
    // span one contiguous 512B region -> 16 lines/wave total).
    const u16x8* ip = (const u16x8*)(nbr16 + (size_t)n * K_);
    u16x8 qa = ip[0], qb = ip[1];
    int idxs[K_];
#pragma unroll
    for (int v = 0; v < 8; ++v) {
        idxs[v]     = qa[v];   // ushort -> int zero-extend
        idxs[8 + v] = qb[v];
    }

    const short* xb = x16 + (size_t)b * (N_ * D_) + chunk * 8;
    const short* bf = lb + lane * 8;

    f32x4 acc0 = {0.f, 0.f, 0.f, 0.f};
    f32x4 acc1 = {0.f, 0.f, 0.f, 0.f};

#pragma unroll
    for (int kk = 0; kk < K_; ++kk) {
        bf16x8 a  = *reinterpret_cast<const bf16x8*>(xb + (size_t)idxs[kk] * D_);
        bf16x8 b0 = *reinterpret_cast<const bf16x8*>(bf + (kk * 2 + 0) * 512);
        bf16x8 b1 = *reinterpret_cast<const bf16x8*>(bf + (kk * 2 + 1) * 512);
        acc0 = __builtin_amdgcn_mfma_f32_16x16x32_bf16(a, b0, acc0, 0, 0, 0);
        acc1 = __builtin_amdgcn_mfma_f32_16x16x32_bf16(a, b1, acc1, 0, 0, 0);
    }

    // epilogue (verified): C col = lane&15, row = (lane>>4)*4 + j
    const float bv0 = bias[r];
    const float bv1 = bias[16 + r];
    const int rowbase = m0 + chunk * 4;
#pragma unroll
    for (int j = 0; j < 4; ++j) {
        const size_t o = (size_t)(rowbase + j) * F_;
        float v0 = acc0[j] + bv0;
        float v1 = acc1[j] + bv1;
        out[o + r]      = v0 > 0.f ? v0 : 0.f;
        out[o + 16 + r] = v1 > 0.f ? v1 : 0.f;
    }
}

// ================= fallback path (verified round-8, needs only 40KB ws) =====

constexpr int DPAD = 40;
constexpr int KSTRIDE = F_ * DPAD;               // 1280 shorts per k-slab

__global__ __launch_bounds__(256) void prep_w8(const float* __restrict__ kern,
                                               short* __restrict__ ws16) {
    int e = blockIdx.x * 256 + threadIdx.x;
    int kk = e >> 10, d = (e >> 5) & 31, f = e & 31;
    ws16[kk * KSTRIDE + f * DPAD + d] = f2bf_rne(kern[e]);
}

__global__ __launch_bounds__(256) void graphconv_mfma8(
    const float* __restrict__ x, const int* __restrict__ nbr,
    const short* __restrict__ ws16, const float* __restrict__ bias,
    float* __restrict__ out)
{
    const bool is64 = (nbr[1] | nbr[3] | nbr[5] | nbr[7] |
                       nbr[9] | nbr[11] | nbr[13] | nbr[15]) == 0;
    const int istride = is64 ? 2 : 1;

    const int lane = threadIdx.x & 63;
    const int wid  = threadIdx.x >> 6;
    const int m0   = blockIdx.x * ROWS_PER_BLOCK + wid * 16;
    const int r = lane & 15, chunk = lane >> 4;
    const int m = m0 + r;
    const int b = m / N_;
    const int n = m - b * N_;

    int idxs[K_];
#pragma unroll
    for (int kk = 0; kk < K_; ++kk)
        idxs[kk] = nbr[(size_t)(n * K_ + kk) * istride];

    const float* xbase = x + (size_t)b * (N_ * D_) + chunk * 8;
    const short* bcol0 = ws16 + r * DPAD + chunk * 8;
    const short* bcol1 = ws16 + (16 + r) * DPAD + chunk * 8;

    f32x4 acc0 = {0.f, 0.f, 0.f, 0.f};
    f32x4 acc1 = {0.f, 0.f, 0.f, 0.f};

#pragma unroll
    for (int kk = 0; kk < K_; ++kk) {
        const float* xr = xbase + (size_t)idxs[kk] * D_;
        f32x4 xa = *reinterpret_cast<const f32x4*>(xr);
        f32x4 xb = *reinterpret_cast<const f32x4*>(xr + 4);
        unsigned p0, p1, p2, p3;
        asm("v_cvt_pk_bf16_f32 %0, %1, %2" : "=v"(p0) : "v"(xa.x), "v"(xa.y));
        asm("v_cvt_pk_bf16_f32 %0, %1, %2" : "=v"(p1) : "v"(xa.z), "v"(xa.w));
        asm("v_cvt_pk_bf16_f32 %0, %1, %2" : "=v"(p2) : "v"(xb.x), "v"(xb.y));
        asm("v_cvt_pk_bf16_f32 %0, %1, %2" : "=v"(p3) : "v"(xb.z), "v"(xb.w));
        union { unsigned u[4]; bf16x8 v; } af;
        af.u[0] = p0; af.u[1] = p1; af.u[2] = p2; af.u[3] = p3;
        bf16x8 b0 = *reinterpret_cast<const bf16x8*>(bcol0 + kk * KSTRIDE);
        bf16x8 b1 = *reinterpret_cast<const bf16x8*>(bcol1 + kk * KSTRIDE);
        acc0 = __builtin_amdgcn_mfma_f32_16x16x32_bf16(af.v, b0, acc0, 0, 0, 0);
        acc1 = __builtin_amdgcn_mfma_f32_16x16x32_bf16(af.v, b1, acc1, 0, 0, 0);
    }

    const float bv0 = bias[r];
    const float bv1 = bias[16 + r];
    const int rowbase = m0 + chunk * 4;
#pragma unroll
    for (int j = 0; j < 4; ++j) {
        const size_t o = (size_t)(rowbase + j) * F_;
        float v0 = acc0[j] + bv0;
        float v1 = acc1[j] + bv1;
        out[o + r]      = v0 > 0.f ? v0 : 0.f;
        out[o + 16 + r] = v1 > 0.f ? v1 : 0.f;
    }
}

// ================= launch =================

extern "C" void kernel_launch(void* const* d_in, const int* in_sizes, int n_in,
                              void* d_out, int out_size, void* d_ws, size_t ws_size,
                              hipStream_t stream) {
    const float* x    = (const float*)d_in[0];
    const int*   nbr  = (const int*)d_in[1];
    const float* kern = (const float*)d_in[2];
    const float* bias = (const float*)d_in[3];
    float* out = (float*)d_out;

    if (ws_size >= WS_NEED) {
        char* ws = (char*)d_ws;
        short* wsf = (short*)(ws + WSF_OFF);
        short* x16 = (short*)(ws + X16_OFF);
        unsigned short* nbr16 = (unsigned short*)(ws + N16_OFF);
        prep_all<<<dim3(1024), 256, 0, stream>>>(x, nbr, kern, wsf, x16, nbr16);
        graphconv_fast<<<dim3(NWG), 256, 0, stream>>>(
            x16, nbr16, wsf, bias, out);
    } else {
        short* ws16 = (short*)d_ws;   // 40960 B
        prep_w8<<<dim3(K_ * D_ * F_ / 256), 256, 0, stream>>>(kern, ws16);
        graphconv_mfma8<<<dim3(NWG), 256, 0, stream>>>(
            x, nbr, ws16, bias, out);
    }
}

// Round 16
// 41.742 us; speedup vs baseline: 2.2198x; 1.0047x over previous
//
#include <hip/hip_runtime.h>
#include <hip/hip_bf16.h>

// GraphConv: out[b,n,f] = relu( sum_{k,d} x[b, nbr[n,k], d] * W[k,d,f] + bias[f] )
// B=4, N=50000, D=32, K=16, F=32.  M = B*N = 200000 rows, contraction = 512.
//
// Round 15 = round 14 (PASS, 42.1us) + ONE change: u16 index compaction.
// Indices < 50000 < 2^16. Prep packs nbr (int64-or-int32) to u16 (6.4MB);
// main reads each row's 16 indices as 2x u16x8 (16 lines/wave vs 128 for
// direct int64). Line-count model (confirmed by r13->r14 delta: 64 lines/wave
// ~ 5us): main -7us, prep +5.3us. Unpack = ushort vector element -> int
// (implicit zero-extend). All else byte-identical to the r14 PASS.

typedef __attribute__((ext_vector_type(8))) short bf16x8;
typedef __attribute__((ext_vector_type(8))) unsigned short u16x8;
typedef __attribute__((ext_vector_type(4))) short s16x4;
typedef __attribute__((ext_vector_type(4))) float f32x4;
typedef __attribute__((ext_vector_type(4))) int   i32x4;

constexpr int B_ = 4, N_ = 50000, D_ = 32, K_ = 16, F_ = 32;
constexpr int M_ = B_ * N_;                      // 200000
constexpr int ROWS_PER_BLOCK = 64;               // 4 waves x 16 rows
constexpr int NWG = M_ / ROWS_PER_BLOCK;         // 3125 blocks

// ---- workspace layout (bytes) ----
constexpr size_t WSF_OFF = 0;                        // 32768 B  (B-fragments)
constexpr size_t X16_OFF = 32768;                    // 12,800,000 B (x bf16)
constexpr size_t N16_OFF = X16_OFF + 12800000;       // 6,400,000 B (nbr u16)
constexpr size_t WS_NEED = N16_OFF + 6400000;        // 19,232,768 B

__device__ __forceinline__ short f2bf_rne(float f) {
    union { float f; unsigned u; } v; v.f = f;
    unsigned r = v.u + 0x7FFFu + ((v.u >> 16) & 1u);
    return (short)(r >> 16);
}

// ================= fast path =================

__global__ __launch_bounds__(256) void prep_all(
    const float* __restrict__ x, const int* __restrict__ nbr,
    const float* __restrict__ kern,
    short* __restrict__ wsf, short* __restrict__ x16,
    unsigned short* __restrict__ nbr16)
{
    const int stride = gridDim.x * 256;
    const int t = blockIdx.x * 256 + threadIdx.x;

    // x: f32 -> bf16, vectorized 4-wide (1,600,000 vec4)
    const f32x4* x4 = (const f32x4*)x;
    s16x4* xo = (s16x4*)x16;
    for (int i = t; i < (B_ * N_ * D_) / 4; i += stride) {
        f32x4 v = x4[i];
        s16x4 o = { f2bf_rne(v.x), f2bf_rne(v.y), f2bf_rne(v.z), f2bf_rne(v.w) };
        xo[i] = o;
    }

    // nbr -> u16 (indices < 50000 < 2^16). int64-or-int32 handled uniformly.
    const bool is64 = (nbr[1] | nbr[3] | nbr[5] | nbr[7] |
                       nbr[9] | nbr[11] | nbr[13] | nbr[15]) == 0;
    if (is64) {
        for (int i = t; i < N_ * K_; i += stride)
            nbr16[i] = (unsigned short)nbr[(size_t)i * 2];
    } else {
        for (int i = t; i < N_ * K_; i += stride)
            nbr16[i] = (unsigned short)nbr[i];
    }

    // W -> wsf, verified fragment-coalesced layout:
    // wsf[((kk*2+h)*64 + lane)*8 + dd] = bf16(kern[kk][(lane>>4)*8+dd][h*16+(lane&15)])
    for (int e = t; e < K_ * D_ * F_; e += stride) {
        int kk = e >> 10, d = (e >> 5) & 31, f = e & 31;
        int h = f >> 4, lane = ((d >> 3) << 4) | (f & 15), dd = d & 7;
        wsf[(((kk * 2 + h) * 64) + lane) * 8 + dd] = f2bf_rne(kern[e]);
    }
}

__global__ __launch_bounds__(256) void graphconv_fast(
    const short* __restrict__ x16, const unsigned short* __restrict__ nbr16,
    const short* __restrict__ wsf, const float* __restrict__ bias,
    float* __restrict__ out)
{
    // identity image of wsf (16384 shorts = 32 KB); ds_read at slab+lane*16
    // is fully sequential per instruction -> LDS-peak, no conflicts.
    __shared__ __align__(16) short lb[K_ * 2 * 64 * 8];
    {
        const bf16x8* src = (const bf16x8*)wsf;
        bf16x8* dst = (bf16x8*)lb;
#pragma unroll
        for (int i = 0; i < 8; ++i)
            dst[threadIdx.x + i * 256] = src[threadIdx.x + i * 256];
    }
    __syncthreads();

    // bijective XCD-chunked swizzle (m204): q=390, rem=5 for NWG=3125.
    const int bid = blockIdx.x;
    const int xcd = bid & 7;
    const int pos = bid >> 3;
    constexpr int q = NWG >> 3, rem = NWG & 7;   // 390, 5
    const int swz = (xcd < rem ? xcd * (q + 1)
                               : rem * (q + 1) + (xcd - rem) * q) + pos;

    const int lane  = threadIdx.x & 63;
    const int wid   = threadIdx.x >> 6;
    const int m0    = swz * ROWS_PER_BLOCK + wid * 16;
    const int r     = lane & 15;   // A-row / B-col this lane serves
    const int chunk = lane >> 4;   // 8-wide d-chunk
    const int m     = m0 + r;
    const int b     = m / N_;
    const int n     = m - b * N_;

    // 16 indices in 2 vector loads (row stream = 32B; 16 consecutive rows
    // span one contiguous 512B region -> 16 lines/wave total).
    const u16x8* ip = (const u16x8*)(nbr16 + (size_t)n * K_);
    u16x8 qa = ip[0], qb = ip[1];
    int idxs[K_];
#pragma unroll
    for (int v = 0; v < 8; ++v) {
        idxs[v]     = qa[v];   // ushort -> int zero-extend
        idxs[8 + v] = qb[v];
    }

    const short* xb = x16 + (size_t)b * (N_ * D_) + chunk * 8;
    const short* bf = lb + lane * 8;

    f32x4 acc0 = {0.f, 0.f, 0.f, 0.f};
    f32x4 acc1 = {0.f, 0.f, 0.f, 0.f};

#pragma unroll
    for (int kk = 0; kk < K_; ++kk) {
        bf16x8 a  = *reinterpret_cast<const bf16x8*>(xb + (size_t)idxs[kk] * D_);
        bf16x8 b0 = *reinterpret_cast<const bf16x8*>(bf + (kk * 2 + 0) * 512);
        bf16x8 b1 = *reinterpret_cast<const bf16x8*>(bf + (kk * 2 + 1) * 512);
        acc0 = __builtin_amdgcn_mfma_f32_16x16x32_bf16(a, b0, acc0, 0, 0, 0);
        acc1 = __builtin_amdgcn_mfma_f32_16x16x32_bf16(a, b1, acc1, 0, 0, 0);
    }

    // epilogue (verified): C col = lane&15, row = (lane>>4)*4 + j
    const float bv0 = bias[r];
    const float bv1 = bias[16 + r];
    const int rowbase = m0 + chunk * 4;
#pragma unroll
    for (int j = 0; j < 4; ++j) {
        const size_t o = (size_t)(rowbase + j) * F_;
        float v0 = acc0[j] + bv0;
        float v1 = acc1[j] + bv1;
        out[o + r]      = v0 > 0.f ? v0 : 0.f;
        out[o + 16 + r] = v1 > 0.f ? v1 : 0.f;
    }
}

// ================= fallback path (verified round-8, needs only 40KB ws) =====

constexpr int DPAD = 40;
constexpr int KSTRIDE = F_ * DPAD;               // 1280 shorts per k-slab

__global__ __launch_bounds__(256) void prep_w8(const float* __restrict__ kern,
                                               short* __restrict__ ws16) {
    int e = blockIdx.x * 256 + threadIdx.x;
    int kk = e >> 10, d = (e >> 5) & 31, f = e & 31;
    ws16[kk * KSTRIDE + f * DPAD + d] = f2bf_rne(kern[e]);
}

__global__ __launch_bounds__(256) void graphconv_mfma8(
    const float* __restrict__ x, const int* __restrict__ nbr,
    const short* __restrict__ ws16, const float* __restrict__ bias,
    float* __restrict__ out)
{
    const bool is64 = (nbr[1] | nbr[3] | nbr[5] | nbr[7] |
                       nbr[9] | nbr[11] | nbr[13] | nbr[15]) == 0;
    const int istride = is64 ? 2 : 1;

    const int lane = threadIdx.x & 63;
    const int wid  = threadIdx.x >> 6;
    const int m0   = blockIdx.x * ROWS_PER_BLOCK + wid * 16;
    const int r = lane & 15, chunk = lane >> 4;
    const int m = m0 + r;
    const int b = m / N_;
    const int n = m - b * N_;

    int idxs[K_];
#pragma unroll
    for (int kk = 0; kk < K_; ++kk)
        idxs[kk] = nbr[(size_t)(n * K_ + kk) * istride];

    const float* xbase = x + (size_t)b * (N_ * D_) + chunk * 8;
    const short* bcol0 = ws16 + r * DPAD + chunk * 8;
    const short* bcol1 = ws16 + (16 + r) * DPAD + chunk * 8;

    f32x4 acc0 = {0.f, 0.f, 0.f, 0.f};
    f32x4 acc1 = {0.f, 0.f, 0.f, 0.f};

#pragma unroll
    for (int kk = 0; kk < K_; ++kk) {
        const float* xr = xbase + (size_t)idxs[kk] * D_;
        f32x4 xa = *reinterpret_cast<const f32x4*>(xr);
        f32x4 xb = *reinterpret_cast<const f32x4*>(xr + 4);
        unsigned p0, p1, p2, p3;
        asm("v_cvt_pk_bf16_f32 %0, %1, %2" : "=v"(p0) : "v"(xa.x), "v"(xa.y));
        asm("v_cvt_pk_bf16_f32 %0, %1, %2" : "=v"(p1) : "v"(xa.z), "v"(xa.w));
        asm("v_cvt_pk_bf16_f32 %0, %1, %2" : "=v"(p2) : "v"(xb.x), "v"(xb.y));
        asm("v_cvt_pk_bf16_f32 %0, %1, %2" : "=v"(p3) : "v"(xb.z), "v"(xb.w));
        union { unsigned u[4]; bf16x8 v; } af;
        af.u[0] = p0; af.u[1] = p1; af.u[2] = p2; af.u[3] = p3;
        bf16x8 b0 = *reinterpret_cast<const bf16x8*>(bcol0 + kk * KSTRIDE);
        bf16x8 b1 = *reinterpret_cast<const bf16x8*>(bcol1 + kk * KSTRIDE);
        acc0 = __builtin_amdgcn_mfma_f32_16x16x32_bf16(af.v, b0, acc0, 0, 0, 0);
        acc1 = __builtin_amdgcn_mfma_f32_16x16x32_bf16(af.v, b1, acc1, 0, 0, 0);
    }

    const float bv0 = bias[r];
    const float bv1 = bias[16 + r];
    const int rowbase = m0 + chunk * 4;
#pragma unroll
    for (int j = 0; j < 4; ++j) {
        const size_t o = (size_t)(rowbase + j) * F_;
        float v0 = acc0[j] + bv0;
        float v1 = acc1[j] + bv1;
        out[o + r]      = v0 > 0.f ? v0 : 0.f;
        out[o + 16 + r] = v1 > 0.f ? v1 : 0.f;
    }
}

// ================= launch =================

extern "C" void kernel_launch(void* const* d_in, const int* in_sizes, int n_in,
                              void* d_out, int out_size, void* d_ws, size_t ws_size,
                              hipStream_t stream) {
    const float* x    = (const float*)d_in[0];
    const int*   nbr  = (const int*)d_in[1];
    const float* kern = (const float*)d_in[2];
    const float* bias = (const float*)d_in[3];
    float* out = (float*)d_out;

    if (ws_size >= WS_NEED) {
        char* ws = (char*)d_ws;
        short* wsf = (short*)(ws + WSF_OFF);
        short* x16 = (short*)(ws + X16_OFF);
        unsigned short* nbr16 = (unsigned short*)(ws + N16_OFF);
        prep_all<<<dim3(1024), 256, 0, stream>>>(x, nbr, kern, wsf, x16, nbr16);
        graphconv_fast<<<dim3(NWG), 256, 0, stream>>>(
            x16, nbr16, wsf, bias, out);
    } else {
        short* ws16 = (short*)d_ws;   // 40960 B
        prep_w8<<<dim3(K_ * D_ * F_ / 256), 256, 0, stream>>>(kern, ws16);
        graphconv_mfma8<<<dim3(NWG), 256, 0, stream>>>(
            x, nbr, ws16, bias, out);
    }
}